// Round 1
// baseline (621.821 us; speedup 1.0000x reference)
//
#include <hip/hip_runtime.h>

// DeepAttention: h = tanh([attn@ctx, x] @ Wout^T-ish), attn = softmax(mask(w . relu(ctx@W^T)))
// Strategy: 3-term bf16-split MFMA logits pass (HBM-bound, ~85us), LDS softmax,
// sparse (near-one-hot) weighted gather, fused h_tilde.

#define BB 128
#define SS 8192
#define DD 128
#define CHROWS 128
#define CHELEMS (CHROWS * DD)
#define NCHUNK 32          // rows per block = 4096, grid.x = 2 slices

typedef float f32x4_t __attribute__((ext_vector_type(4)));
typedef short bf16x8_t __attribute__((ext_vector_type(8)));
typedef unsigned short u16x4_t __attribute__((ext_vector_type(4)));
typedef unsigned short u16x8_t __attribute__((ext_vector_type(8)));

__device__ __forceinline__ unsigned short f2bf(float x) {
  unsigned u = __builtin_bit_cast(unsigned, x);
  unsigned r = (u + 0x7FFFu + ((u >> 16) & 1u)) >> 16;
  return (unsigned short)r;
}
__device__ __forceinline__ float bf2f(unsigned short h) {
  unsigned u = ((unsigned)h) << 16;
  return __builtin_bit_cast(float, u);
}

// ---- K0: detect mask storage format (0 = int32, 1 = uint8, 2 = float32) ----
// Reads only the first 1 MB (safe under all interpretations).
__global__ void k_detect(const unsigned int* __restrict__ mw, unsigned int* __restrict__ flag) {
  int i = blockIdx.x * 256 + threadIdx.x;   // 1024 blocks -> 262144 words = 1 MB
  unsigned v = mw[i];
  unsigned f = 0;
  if (v == 0x3F800000u) f = 2u;             // f32 1.0 pattern
  else if (v > 1u) f = 1u;                  // packed uint8 bools
  if (f) atomicOr(flag, f);
}

// ---- K1a: split W into bf16 hi/lo ----
__global__ void k_splitW(const float* __restrict__ Wg, unsigned short* __restrict__ Whi,
                         unsigned short* __restrict__ Wlo) {
  int i = blockIdx.x * 256 + threadIdx.x;   // 64 blocks -> 16384
  float x = Wg[i];
  unsigned short h = f2bf(x);
  Whi[i] = h;
  Wlo[i] = f2bf(x - bf2f(h));
}

// ---- K1b: w[b,e] = relu(x@W^T)[b,e] * V[e], fp32 exact ----
__global__ void k_w(const float* __restrict__ inp, const float* __restrict__ Wg,
                    const float* __restrict__ Vg, float* __restrict__ wv) {
  int b = blockIdx.x, e = threadIdx.x;
  __shared__ float xin[DD];
  xin[e] = inp[b * DD + e];
  __syncthreads();
  const float* wr = Wg + e * DD;
  float s = 0.f;
#pragma unroll 8
  for (int d = 0; d < DD; ++d) s += xin[d] * wr[d];
  wv[b * DD + e] = fmaxf(s, 0.f) * Vg[e];
}

// ---- K2: logits[b,s] = sum_e w[b,e]*relu(sum_d ctx[b,s,d]*W[e,d]) ----
// bf16 3-term split: chi@Whi + chi@Wlo + clo@Whi  (effective ~17-bit precision)
__launch_bounds__(512, 2)
__global__ void k_logits(const float* __restrict__ ctx, const unsigned short* __restrict__ Whi,
                         const unsigned short* __restrict__ Wlo, const float* __restrict__ wv,
                         float* __restrict__ logits) {
  // LDS: W hi/lo packed in MFMA-fragment order (conflict-free b128 reads),
  //      ctx hi/lo row-major with XOR swizzle (col ^ ((row&15)<<3)).
  __shared__ unsigned short smem[4 * 16384];   // 128 KiB
  __shared__ float wl[DD];
  unsigned short* WPKH = smem;
  unsigned short* WPKL = smem + 16384;
  unsigned short* CHI  = smem + 32768;
  unsigned short* CLO  = smem + 49152;

  const int tid = threadIdx.x;
  const int b = blockIdx.y;
  const int slice = blockIdx.x;                 // 0..1
  const long base = ((long)b * SS + (long)slice * (NCHUNK * CHROWS)) * DD;

  f32x4_t rg[8];
  auto issue = [&](int ch) {
#pragma unroll
    for (int j = 0; j < 8; ++j) {
      int f4 = tid + j * 512;
      rg[j] = *(const f32x4_t*)(ctx + base + (long)ch * CHELEMS + (long)f4 * 4);
    }
  };
  issue(0);   // get chunk-0 loads in flight before W staging

  // Stage W hi/lo into packed-fragment layout. Packed unit p (16B) = frag p>>6, lane p&63.
#pragma unroll
  for (int jj = 0; jj < 4; ++jj) {
    int p = tid + jj * 512;                     // 2048 units per array
    int frag = p >> 6;                          // et*4 + ks
    int li = p & 63;
    int et = frag >> 2, ks = frag & 3;
    int lg = li >> 4, lr = li & 15;
    int src = (et * 16 + lr) * DD + ks * 32 + lg * 8;
    *(u16x8_t*)(&WPKH[p * 8]) = *(const u16x8_t*)(&Whi[src]);
    *(u16x8_t*)(&WPKL[p * 8]) = *(const u16x8_t*)(&Wlo[src]);
  }
  if (tid < DD) wl[tid] = wv[b * DD + tid];

  const int wave = tid >> 6;
  const int lane = tid & 63;
  const int lr = lane & 15;
  const int lg = lane >> 4;

  for (int ch = 0; ch < NCHUNK; ++ch) {
    // convert chunk ch (regs) -> LDS hi/lo, swizzled
#pragma unroll
    for (int j = 0; j < 8; ++j) {
      int f4 = tid + j * 512;
      int r = f4 >> 5;
      int cw = (f4 & 31) << 2;
      f32x4_t x = rg[j];
      u16x4_t hh, ll;
#pragma unroll
      for (int k = 0; k < 4; ++k) {
        unsigned short hv = f2bf(x[k]);
        hh[k] = hv;
        ll[k] = f2bf(x[k] - bf2f(hv));
      }
      int idx = r * DD + (cw ^ ((r & 15) << 3));
      *(u16x4_t*)(&CHI[idx]) = hh;
      *(u16x4_t*)(&CLO[idx]) = ll;
    }
    if (ch < NCHUNK - 1) issue(ch + 1);         // prefetch next chunk under compute
    __syncthreads();

    // compute: wave owns 16 rows [wave*16, wave*16+16)
    const int wrow = wave * 16;
    bf16x8_t ahi[4], alo[4];
    {
      int r = wrow + lr;
      int sw = (r & 15) << 3;
#pragma unroll
      for (int ks = 0; ks < 4; ++ks) {
        int c = ks * 32 + lg * 8;
        ahi[ks] = *(const bf16x8_t*)(&CHI[r * DD + (c ^ sw)]);
        alo[ks] = *(const bf16x8_t*)(&CLO[r * DD + (c ^ sw)]);
      }
    }
    float part0 = 0.f, part1 = 0.f, part2 = 0.f, part3 = 0.f;
#pragma unroll 2
    for (int et = 0; et < 8; ++et) {
      f32x4_t a1 = {0.f, 0.f, 0.f, 0.f};
      f32x4_t a2 = a1, a3 = a1;
#pragma unroll
      for (int ks = 0; ks < 4; ++ks) {
        const int pidx = ((((et << 2) | ks) << 6) | lane) << 3;
        bf16x8_t bh = *(const bf16x8_t*)(&WPKH[pidx]);
        bf16x8_t bl = *(const bf16x8_t*)(&WPKL[pidx]);
        a1 = __builtin_amdgcn_mfma_f32_16x16x32_bf16(ahi[ks], bh, a1, 0, 0, 0);
        a2 = __builtin_amdgcn_mfma_f32_16x16x32_bf16(ahi[ks], bl, a2, 0, 0, 0);
        a3 = __builtin_amdgcn_mfma_f32_16x16x32_bf16(alo[ks], bh, a3, 0, 0, 0);
      }
      float wf = wl[et * 16 + lr];              // C col = lane&15 -> e = et*16+lr
      part0 += wf * fmaxf(a1[0] + a2[0] + a3[0], 0.f);
      part1 += wf * fmaxf(a1[1] + a2[1] + a3[1], 0.f);
      part2 += wf * fmaxf(a1[2] + a2[2] + a3[2], 0.f);
      part3 += wf * fmaxf(a1[3] + a2[3] + a3[3], 0.f);
    }
    // butterfly over the 16 lanes sharing rows (low-4 lane bits vary e)
#pragma unroll
    for (int m = 1; m < 16; m <<= 1) {
      part0 += __shfl_xor(part0, m, 64);
      part1 += __shfl_xor(part1, m, 64);
      part2 += __shfl_xor(part2, m, 64);
      part3 += __shfl_xor(part3, m, 64);
    }
    if (lr == 0) {                              // C row = 4*lg + i
      long so = (long)b * SS + (long)slice * (NCHUNK * CHROWS) + ch * CHROWS + wrow + lg * 4;
      logits[so + 0] = part0;
      logits[so + 1] = part1;
      logits[so + 2] = part2;
      logits[so + 3] = part3;
    }
    __syncthreads();
  }
}

// ---- K3: masked softmax over S per batch, in place over logits ----
__global__ void k_softmax(const float* __restrict__ logits, const void* __restrict__ mask,
                          const unsigned int* __restrict__ flag, float* __restrict__ attn) {
  const int b = blockIdx.x;
  const int tid = threadIdx.x;                  // 256
  __shared__ float buf[SS];                     // 32 KiB
  __shared__ float red[4];
  const unsigned mode = *flag;
  const long off = (long)b * SS;
  float mx = -3.4e38f;
  for (int i = tid; i < SS; i += 256) {
    float v = logits[off + i];
    bool m;
    if (mode == 0)      m = ((const int*)mask)[off + i] != 0;
    else if (mode == 1) m = ((const unsigned char*)mask)[off + i] != 0;
    else                m = ((const float*)mask)[off + i] != 0.f;
    if (m) v = -1e12f;
    buf[i] = v;
    mx = fmaxf(mx, v);
  }
#pragma unroll
  for (int m2 = 32; m2; m2 >>= 1) mx = fmaxf(mx, __shfl_xor(mx, m2, 64));
  if ((tid & 63) == 0) red[tid >> 6] = mx;
  __syncthreads();
  mx = fmaxf(fmaxf(red[0], red[1]), fmaxf(red[2], red[3]));
  float sum = 0.f;
  for (int i = tid; i < SS; i += 256) {
    float e = expf(buf[i] - mx);
    buf[i] = e;
    sum += e;
  }
#pragma unroll
  for (int m2 = 32; m2; m2 >>= 1) sum += __shfl_xor(sum, m2, 64);
  __syncthreads();
  if ((tid & 63) == 0) red[tid >> 6] = sum;
  __syncthreads();
  float inv = 1.f / (red[0] + red[1] + red[2] + red[3]);
  for (int i = tid; i < SS; i += 256) attn[off + i] = buf[i] * inv;
}

// ---- K4: weighted = attn@ctx via sparse gather (attn near-one-hot), then h = tanh([weighted,x]@Wout^T) ----
__global__ void k_weighted(const float* __restrict__ attn, const float* __restrict__ ctx,
                           const float* __restrict__ inp, const float* __restrict__ Wout,
                           float* __restrict__ hout) {
  const int b = blockIdx.x;
  const int tid = threadIdx.x;                  // 128
  __shared__ unsigned short slist[SS];
  __shared__ float plist[SS];
  __shared__ unsigned cnt;
  __shared__ float wsh[DD], xin[DD];
  if (tid == 0) cnt = 0;
  __syncthreads();
  const long off = (long)b * SS;
  for (int i = tid; i < SS; i += DD) {
    float p = attn[off + i];
    if (p > 1e-8f) {                            // skipped mass <= 8192*1e-8*|ctx| ~ 5e-4
      unsigned k = atomicAdd(&cnt, 1u);
      slist[k] = (unsigned short)i;
      plist[k] = p;
    }
  }
  __syncthreads();
  const int n = (int)cnt;
  float acc = 0.f;
  for (int k = 0; k < n; ++k)
    acc += plist[k] * ctx[(off + slist[k]) * DD + tid];
  wsh[tid] = acc;
  xin[tid] = inp[b * DD + tid];
  __syncthreads();
  const float* wr = Wout + tid * (2 * DD);
  float s = 0.f;
#pragma unroll 8
  for (int f = 0; f < DD; ++f) s += wsh[f] * wr[f];
#pragma unroll 8
  for (int f = 0; f < DD; ++f) s += xin[f] * wr[DD + f];
  hout[b * DD + tid] = tanhf(s);
}

extern "C" void kernel_launch(void* const* d_in, const int* in_sizes, int n_in,
                              void* d_out, int out_size, void* d_ws, size_t ws_size,
                              hipStream_t stream) {
  const float* inp  = (const float*)d_in[0];
  const float* ctx  = (const float*)d_in[1];
  const void*  mask = d_in[2];
  const float* Wg   = (const float*)d_in[3];
  const float* Vg   = (const float*)d_in[4];
  const float* Wout = (const float*)d_in[5];

  float* out = (float*)d_out;
  float* h_out = out;                 // [B, D]
  float* attn_out = out + BB * DD;    // [B, S]  (K2 writes raw logits here, K3 normalizes in place)

  char* ws = (char*)d_ws;
  unsigned int*   flag = (unsigned int*)ws;
  unsigned short* Whi  = (unsigned short*)(ws + 1024);
  unsigned short* Wlo  = (unsigned short*)(ws + 1024 + 32768);
  float*          wv   = (float*)(ws + 1024 + 65536);

  hipMemsetAsync(flag, 0, 4, stream);
  k_detect <<<dim3(1024), dim3(256), 0, stream>>>((const unsigned int*)mask, flag);
  k_splitW <<<dim3(64),   dim3(256), 0, stream>>>(Wg, Whi, Wlo);
  k_w      <<<dim3(BB),   dim3(DD),  0, stream>>>(inp, Wg, Vg, wv);
  k_logits <<<dim3(2, BB), dim3(512), 0, stream>>>(ctx, Whi, Wlo, wv, attn_out);
  k_softmax<<<dim3(BB),   dim3(256), 0, stream>>>(attn_out, mask, flag, attn_out);
  k_weighted<<<dim3(BB),  dim3(DD),  0, stream>>>(attn_out, ctx, inp, Wout, h_out);
}

// Round 2
// 259.672 us; speedup vs baseline: 2.3946x; 2.3946x over previous
//
#include <hip/hip_runtime.h>

// DeepAttention: h = tanh([attn@ctx, x] @ Wout^T-ish), attn = softmax(mask(w . relu(ctx@W^T)))
// Strategy: 3-term bf16-split MFMA logits pass (HBM-bound), LDS softmax,
// parallel sparse weighted gather (2048 blocks -> [B][16][D] partials), fused h_tilde.

#define BB 128
#define SS 8192
#define DD 128
#define CHROWS 128
#define CHELEMS (CHROWS * DD)
#define NCHUNK 32          // rows per block = 4096, grid.x = 2 slices
#define WCH 16             // S-chunks for the weighted gather
#define WLEN (SS / WCH)    // 512 positions per gather block

typedef float f32x4_t __attribute__((ext_vector_type(4)));
typedef short bf16x8_t __attribute__((ext_vector_type(8)));
typedef unsigned short u16x4_t __attribute__((ext_vector_type(4)));
typedef unsigned short u16x8_t __attribute__((ext_vector_type(8)));

__device__ __forceinline__ unsigned short f2bf(float x) {
  unsigned u = __builtin_bit_cast(unsigned, x);
  unsigned r = (u + 0x7FFFu + ((u >> 16) & 1u)) >> 16;
  return (unsigned short)r;
}
__device__ __forceinline__ float bf2f(unsigned short h) {
  unsigned u = ((unsigned)h) << 16;
  return __builtin_bit_cast(float, u);
}

// ---- K0: detect mask storage format (0 = int32, 1 = uint8, 2 = float32) ----
__global__ void k_detect(const unsigned int* __restrict__ mw, unsigned int* __restrict__ flag) {
  int i = blockIdx.x * 256 + threadIdx.x;   // 1024 blocks -> 262144 words = 1 MB
  unsigned v = mw[i];
  unsigned f = 0;
  if (v == 0x3F800000u) f = 2u;             // f32 1.0 pattern
  else if (v > 1u) f = 1u;                  // packed uint8 bools
  if (f) atomicOr(flag, f);
}

// ---- K1a: split W into bf16 hi/lo ----
__global__ void k_splitW(const float* __restrict__ Wg, unsigned short* __restrict__ Whi,
                         unsigned short* __restrict__ Wlo) {
  int i = blockIdx.x * 256 + threadIdx.x;   // 64 blocks -> 16384
  float x = Wg[i];
  unsigned short h = f2bf(x);
  Whi[i] = h;
  Wlo[i] = f2bf(x - bf2f(h));
}

// ---- K1b: w[b,e] = relu(x@W^T)[b,e] * V[e], fp32 exact ----
__global__ void k_w(const float* __restrict__ inp, const float* __restrict__ Wg,
                    const float* __restrict__ Vg, float* __restrict__ wv) {
  int b = blockIdx.x, e = threadIdx.x;
  __shared__ float xin[DD];
  xin[e] = inp[b * DD + e];
  __syncthreads();
  const float* wr = Wg + e * DD;
  float s = 0.f;
#pragma unroll 8
  for (int d = 0; d < DD; ++d) s += xin[d] * wr[d];
  wv[b * DD + e] = fmaxf(s, 0.f) * Vg[e];
}

// ---- K2: logits[b,s] = sum_e w[b,e]*relu(sum_d ctx[b,s,d]*W[e,d]) ----
// bf16 3-term split: chi@Whi + chi@Wlo + clo@Whi  (effective ~17-bit precision)
__launch_bounds__(512, 2)
__global__ void k_logits(const float* __restrict__ ctx, const unsigned short* __restrict__ Whi,
                         const unsigned short* __restrict__ Wlo, const float* __restrict__ wv,
                         float* __restrict__ logits) {
  __shared__ unsigned short smem[4 * 16384];   // 128 KiB
  __shared__ float wl[DD];
  unsigned short* WPKH = smem;
  unsigned short* WPKL = smem + 16384;
  unsigned short* CHI  = smem + 32768;
  unsigned short* CLO  = smem + 49152;

  const int tid = threadIdx.x;
  const int b = blockIdx.y;
  const int slice = blockIdx.x;                 // 0..1
  const long base = ((long)b * SS + (long)slice * (NCHUNK * CHROWS)) * DD;

  f32x4_t rg[8];
  auto issue = [&](int ch) {
#pragma unroll
    for (int j = 0; j < 8; ++j) {
      int f4 = tid + j * 512;
      rg[j] = *(const f32x4_t*)(ctx + base + (long)ch * CHELEMS + (long)f4 * 4);
    }
  };
  issue(0);   // get chunk-0 loads in flight before W staging

  // Stage W hi/lo into packed-fragment layout. Packed unit p (16B) = frag p>>6, lane p&63.
#pragma unroll
  for (int jj = 0; jj < 4; ++jj) {
    int p = tid + jj * 512;                     // 2048 units per array
    int frag = p >> 6;                          // et*4 + ks
    int li = p & 63;
    int et = frag >> 2, ks = frag & 3;
    int lg = li >> 4, lr = li & 15;
    int src = (et * 16 + lr) * DD + ks * 32 + lg * 8;
    *(u16x8_t*)(&WPKH[p * 8]) = *(const u16x8_t*)(&Whi[src]);
    *(u16x8_t*)(&WPKL[p * 8]) = *(const u16x8_t*)(&Wlo[src]);
  }
  if (tid < DD) wl[tid] = wv[b * DD + tid];

  const int wave = tid >> 6;
  const int lane = tid & 63;
  const int lr = lane & 15;
  const int lg = lane >> 4;

  for (int ch = 0; ch < NCHUNK; ++ch) {
    // convert chunk ch (regs) -> LDS hi/lo, swizzled
#pragma unroll
    for (int j = 0; j < 8; ++j) {
      int f4 = tid + j * 512;
      int r = f4 >> 5;
      int cw = (f4 & 31) << 2;
      f32x4_t x = rg[j];
      u16x4_t hh, ll;
#pragma unroll
      for (int k = 0; k < 4; ++k) {
        unsigned short hv = f2bf(x[k]);
        hh[k] = hv;
        ll[k] = f2bf(x[k] - bf2f(hv));
      }
      int idx = r * DD + (cw ^ ((r & 15) << 3));
      *(u16x4_t*)(&CHI[idx]) = hh;
      *(u16x4_t*)(&CLO[idx]) = ll;
    }
    if (ch < NCHUNK - 1) issue(ch + 1);         // prefetch next chunk under compute
    __syncthreads();

    // compute: wave owns 16 rows [wave*16, wave*16+16)
    const int wrow = wave * 16;
    bf16x8_t ahi[4], alo[4];
    {
      int r = wrow + lr;
      int sw = (r & 15) << 3;
#pragma unroll
      for (int ks = 0; ks < 4; ++ks) {
        int c = ks * 32 + lg * 8;
        ahi[ks] = *(const bf16x8_t*)(&CHI[r * DD + (c ^ sw)]);
        alo[ks] = *(const bf16x8_t*)(&CLO[r * DD + (c ^ sw)]);
      }
    }
    float part0 = 0.f, part1 = 0.f, part2 = 0.f, part3 = 0.f;
#pragma unroll 2
    for (int et = 0; et < 8; ++et) {
      f32x4_t a1 = {0.f, 0.f, 0.f, 0.f};
      f32x4_t a2 = a1, a3 = a1;
#pragma unroll
      for (int ks = 0; ks < 4; ++ks) {
        const int pidx = ((((et << 2) | ks) << 6) | lane) << 3;
        bf16x8_t bh = *(const bf16x8_t*)(&WPKH[pidx]);
        bf16x8_t bl = *(const bf16x8_t*)(&WPKL[pidx]);
        a1 = __builtin_amdgcn_mfma_f32_16x16x32_bf16(ahi[ks], bh, a1, 0, 0, 0);
        a2 = __builtin_amdgcn_mfma_f32_16x16x32_bf16(ahi[ks], bl, a2, 0, 0, 0);
        a3 = __builtin_amdgcn_mfma_f32_16x16x32_bf16(alo[ks], bh, a3, 0, 0, 0);
      }
      float wf = wl[et * 16 + lr];              // C col = lane&15 -> e = et*16+lr
      part0 += wf * fmaxf(a1[0] + a2[0] + a3[0], 0.f);
      part1 += wf * fmaxf(a1[1] + a2[1] + a3[1], 0.f);
      part2 += wf * fmaxf(a1[2] + a2[2] + a3[2], 0.f);
      part3 += wf * fmaxf(a1[3] + a2[3] + a3[3], 0.f);
    }
#pragma unroll
    for (int m = 1; m < 16; m <<= 1) {
      part0 += __shfl_xor(part0, m, 64);
      part1 += __shfl_xor(part1, m, 64);
      part2 += __shfl_xor(part2, m, 64);
      part3 += __shfl_xor(part3, m, 64);
    }
    if (lr == 0) {                              // C row = 4*lg + i
      long so = (long)b * SS + (long)slice * (NCHUNK * CHROWS) + ch * CHROWS + wrow + lg * 4;
      logits[so + 0] = part0;
      logits[so + 1] = part1;
      logits[so + 2] = part2;
      logits[so + 3] = part3;
    }
    __syncthreads();
  }
}

// ---- K3: masked softmax over S per batch, in place over logits ----
__global__ void k_softmax(const float* __restrict__ logits, const void* __restrict__ mask,
                          const unsigned int* __restrict__ flag, float* __restrict__ attn) {
  const int b = blockIdx.x;
  const int tid = threadIdx.x;                  // 256
  __shared__ float buf[SS];                     // 32 KiB
  __shared__ float red[4];
  const unsigned mode = *flag;
  const long off = (long)b * SS;
  float mx = -3.4e38f;
  for (int i = tid; i < SS; i += 256) {
    float v = logits[off + i];
    bool m;
    if (mode == 0)      m = ((const int*)mask)[off + i] != 0;
    else if (mode == 1) m = ((const unsigned char*)mask)[off + i] != 0;
    else                m = ((const float*)mask)[off + i] != 0.f;
    if (m) v = -1e12f;
    buf[i] = v;
    mx = fmaxf(mx, v);
  }
#pragma unroll
  for (int m2 = 32; m2; m2 >>= 1) mx = fmaxf(mx, __shfl_xor(mx, m2, 64));
  if ((tid & 63) == 0) red[tid >> 6] = mx;
  __syncthreads();
  mx = fmaxf(fmaxf(red[0], red[1]), fmaxf(red[2], red[3]));
  float sum = 0.f;
  for (int i = tid; i < SS; i += 256) {
    float e = expf(buf[i] - mx);
    buf[i] = e;
    sum += e;
  }
#pragma unroll
  for (int m2 = 32; m2; m2 >>= 1) sum += __shfl_xor(sum, m2, 64);
  __syncthreads();
  if ((tid & 63) == 0) red[tid >> 6] = sum;
  __syncthreads();
  float inv = 1.f / (red[0] + red[1] + red[2] + red[3]);
  for (int i = tid; i < SS; i += 256) attn[off + i] = buf[i] * inv;
}

// ---- K4: partial weighted sums. grid (B, WCH), 256 thr. wpart[b][c][d] ----
__global__ void k_wpartial(const float* __restrict__ attn, const float* __restrict__ ctx,
                           float* __restrict__ wpart) {
  const int b = blockIdx.x, c = blockIdx.y;
  const int tid = threadIdx.x;                  // 256
  __shared__ unsigned short slist[WLEN];
  __shared__ float plist[WLEN];
  __shared__ float part[256];
  __shared__ unsigned cnt;
  if (tid == 0) cnt = 0;
  __syncthreads();
  const long off = (long)b * SS + (long)c * WLEN;
  for (int i = tid; i < WLEN; i += 256) {
    float p = attn[off + i];
    if (p > 1e-8f) {                            // skipped mass <= 8192*1e-8*|ctx| ~ 5e-4
      unsigned k = atomicAdd(&cnt, 1u);
      slist[k] = (unsigned short)i;
      plist[k] = p;
    }
  }
  __syncthreads();
  const int n = (int)cnt;
  const int d = tid & 127;
  const int g = tid >> 7;                       // 2 row-groups
  float a0 = 0.f, a1 = 0.f, a2 = 0.f, a3 = 0.f;
  int k = g;
  for (; k + 6 < n; k += 8) {
    a0 += plist[k]     * ctx[(off + slist[k])     * DD + d];
    a1 += plist[k + 2] * ctx[(off + slist[k + 2]) * DD + d];
    a2 += plist[k + 4] * ctx[(off + slist[k + 4]) * DD + d];
    a3 += plist[k + 6] * ctx[(off + slist[k + 6]) * DD + d];
  }
  for (; k < n; k += 2)
    a0 += plist[k] * ctx[(off + slist[k]) * DD + d];
  part[tid] = (a0 + a1) + (a2 + a3);
  __syncthreads();
  if (tid < 128)
    wpart[((long)b * WCH + c) * DD + tid] = part[tid] + part[tid + 128];
}

// ---- K5: reduce partials, h = tanh([weighted,x]@Wout^T) ----
__global__ void k_out(const float* __restrict__ wpart, const float* __restrict__ inp,
                      const float* __restrict__ Wout, float* __restrict__ hout) {
  const int b = blockIdx.x;
  const int tid = threadIdx.x;                  // 128
  __shared__ float wsh[DD], xin[DD];
  float acc = 0.f;
#pragma unroll
  for (int cc = 0; cc < WCH; ++cc)
    acc += wpart[((long)b * WCH + cc) * DD + tid];
  wsh[tid] = acc;
  xin[tid] = inp[b * DD + tid];
  __syncthreads();
  const float* wr = Wout + tid * (2 * DD);
  float s = 0.f;
#pragma unroll 8
  for (int f = 0; f < DD; ++f) s += wsh[f] * wr[f];
#pragma unroll 8
  for (int f = 0; f < DD; ++f) s += xin[f] * wr[DD + f];
  hout[b * DD + tid] = tanhf(s);
}

extern "C" void kernel_launch(void* const* d_in, const int* in_sizes, int n_in,
                              void* d_out, int out_size, void* d_ws, size_t ws_size,
                              hipStream_t stream) {
  const float* inp  = (const float*)d_in[0];
  const float* ctx  = (const float*)d_in[1];
  const void*  mask = d_in[2];
  const float* Wg   = (const float*)d_in[3];
  const float* Vg   = (const float*)d_in[4];
  const float* Wout = (const float*)d_in[5];

  float* out = (float*)d_out;
  float* h_out = out;                 // [B, D]
  float* attn_out = out + BB * DD;    // [B, S]  (K2 writes raw logits here, K3 normalizes in place)

  char* ws = (char*)d_ws;
  unsigned int*   flag  = (unsigned int*)ws;
  unsigned short* Whi   = (unsigned short*)(ws + 1024);
  unsigned short* Wlo   = (unsigned short*)(ws + 1024 + 32768);
  float*          wv    = (float*)(ws + 1024 + 65536);
  float*          wpart = (float*)(ws + 1024 + 65536 + 65536);   // [B][WCH][DD] = 1 MB

  hipMemsetAsync(flag, 0, 4, stream);
  k_detect  <<<dim3(1024),    dim3(256), 0, stream>>>((const unsigned int*)mask, flag);
  k_splitW  <<<dim3(64),      dim3(256), 0, stream>>>(Wg, Whi, Wlo);
  k_w       <<<dim3(BB),      dim3(DD),  0, stream>>>(inp, Wg, Vg, wv);
  k_logits  <<<dim3(2, BB),   dim3(512), 0, stream>>>(ctx, Whi, Wlo, wv, attn_out);
  k_softmax <<<dim3(BB),      dim3(256), 0, stream>>>(attn_out, mask, flag, attn_out);
  k_wpartial<<<dim3(BB, WCH), dim3(256), 0, stream>>>(attn_out, ctx, wpart);
  k_out     <<<dim3(BB),      dim3(128), 0, stream>>>(wpart, inp, Wout, h_out);
}

// Round 4
// 254.491 us; speedup vs baseline: 2.4434x; 1.0204x over previous
//
#include <hip/hip_runtime.h>

// DeepAttention: h = tanh([attn@ctx, x] @ Wout^T-ish), attn = softmax(mask(w . relu(ctx@W^T)))
// R3: k_logits v2 — 2-term bf16 split (ctx_hi@W_hi + ctx_hi@W_lo), 256-row chunks with
// B-frag register reuse (halves LDS W traffic), raw s_barrier so prefetch loads stay in
// flight across the chunk boundary (no vmcnt(0) drain).

#define BB 128
#define SS 8192
#define DD 128
#define CHROWS 256
#define CHELEMS (CHROWS * DD)
#define NCHUNK 16          // 16 chunks * 256 rows = 4096 rows per block, grid.x = 2 slices
#define WCH 16             // S-chunks for the weighted gather
#define WLEN (SS / WCH)    // 512 positions per gather block

typedef float f32x4_t __attribute__((ext_vector_type(4)));
typedef short bf16x8_t __attribute__((ext_vector_type(8)));
typedef unsigned short u16x8_t __attribute__((ext_vector_type(8)));
typedef unsigned int u32x2_t __attribute__((ext_vector_type(2)));

__device__ __forceinline__ unsigned short f2bf(float x) {
  unsigned u = __builtin_bit_cast(unsigned, x);
  unsigned r = (u + 0x7FFFu + ((u >> 16) & 1u)) >> 16;
  return (unsigned short)r;
}
__device__ __forceinline__ float bf2f(unsigned short h) {
  unsigned u = ((unsigned)h) << 16;
  return __builtin_bit_cast(float, u);
}
__device__ __forceinline__ unsigned cvt2bf(float a, float b) {
  return (unsigned)f2bf(a) | ((unsigned)f2bf(b) << 16);      // low16 = a, high16 = b
}

// ---- K0: detect mask storage format (0 = int32, 1 = uint8, 2 = float32) ----
__global__ void k_detect(const unsigned int* __restrict__ mw, unsigned int* __restrict__ flag) {
  int i = blockIdx.x * 256 + threadIdx.x;   // 1024 blocks -> 262144 words = 1 MB
  unsigned v = mw[i];
  unsigned f = 0;
  if (v == 0x3F800000u) f = 2u;             // f32 1.0 pattern
  else if (v > 1u) f = 1u;                  // packed uint8 bools
  if (f) atomicOr(flag, f);
}

// ---- K1a: split W into bf16 hi/lo (W accurate to ~16 mantissa bits) ----
__global__ void k_splitW(const float* __restrict__ Wg, unsigned short* __restrict__ Whi,
                         unsigned short* __restrict__ Wlo) {
  int i = blockIdx.x * 256 + threadIdx.x;   // 64 blocks -> 16384
  float x = Wg[i];
  unsigned short h = f2bf(x);
  Whi[i] = h;
  Wlo[i] = f2bf(x - bf2f(h));
}

// ---- K1b: w[b,e] = relu(x@W^T)[b,e] * V[e], fp32 exact ----
__global__ void k_w(const float* __restrict__ inp, const float* __restrict__ Wg,
                    const float* __restrict__ Vg, float* __restrict__ wv) {
  int b = blockIdx.x, e = threadIdx.x;
  __shared__ float xin[DD];
  xin[e] = inp[b * DD + e];
  __syncthreads();
  const float* wr = Wg + e * DD;
  float s = 0.f;
#pragma unroll 8
  for (int d = 0; d < DD; ++d) s += xin[d] * wr[d];
  wv[b * DD + e] = fmaxf(s, 0.f) * Vg[e];
}

// ---- K2 v2: logits[b,s] = sum_e w[b,e]*relu(sum_d ctx[b,s,d]*W[e,d]) ----
// 2-term: chi@Whi + chi@Wlo. 256-row chunks, B-frags reused across 2 row-tiles/wave.
__launch_bounds__(512, 2)
__global__ void k_logits(const float* __restrict__ ctx, const unsigned short* __restrict__ Whi,
                         const unsigned short* __restrict__ Wlo, const float* __restrict__ wv,
                         float* __restrict__ logits) {
  // LDS: W hi/lo packed in MFMA-fragment order (32 KB each), ctx-hi bf16 [256][128]
  // row-major XOR-swizzled (64 KB). Total 128.5 KB -> 1 block/CU, 8 waves.
  __shared__ unsigned short smem[65536];
  __shared__ float wl[DD];
  unsigned short* WPKH = smem;               // 16384 halves
  unsigned short* WPKL = smem + 16384;
  unsigned short* CHI  = smem + 32768;       // 32768 halves = [256][128]

  const int tid = threadIdx.x;
  const int b = blockIdx.y;
  const int slice = blockIdx.x;              // 0..1
  const long base = ((long)b * SS + (long)slice * (NCHUNK * CHROWS)) * DD;

  f32x4_t rg[16];
  auto issue = [&](int ch) {
#pragma unroll
    for (int j = 0; j < 16; ++j) {
      int f4 = tid + j * 512;
      rg[j] = *(const f32x4_t*)(ctx + base + (long)ch * CHELEMS + (long)f4 * 4);
    }
  };
  issue(0);   // chunk-0 loads in flight under W staging

  // Stage W hi/lo into packed-fragment layout. Packed unit p (16B) = frag p>>6, lane p&63.
#pragma unroll
  for (int jj = 0; jj < 4; ++jj) {
    int p = tid + jj * 512;                  // 2048 units per array
    int frag = p >> 6;                       // et*4 + ks
    int li = p & 63;
    int et = frag >> 2, ks = frag & 3;
    int lg2 = li >> 4, lr2 = li & 15;
    int src = (et * 16 + lr2) * DD + ks * 32 + lg2 * 8;
    *(u16x8_t*)(&WPKH[p * 8]) = *(const u16x8_t*)(&Whi[src]);
    *(u16x8_t*)(&WPKL[p * 8]) = *(const u16x8_t*)(&Wlo[src]);
  }
  if (tid < DD) wl[tid] = wv[b * DD + tid];
  __syncthreads();

  const int wave = tid >> 6;
  const int lane = tid & 63;
  const int lr = lane & 15;
  const int lg = lane >> 4;

  float wfreg[8];
#pragma unroll
  for (int et = 0; et < 8; ++et) wfreg[et] = wl[et * 16 + lr];

  for (int ch = 0; ch < NCHUNK; ++ch) {
    // ---- stage: convert chunk (regs) -> CHI bf16, swizzled ----
#pragma unroll
    for (int j = 0; j < 16; ++j) {
      int f4 = tid + j * 512;
      int r = f4 >> 5;
      int cw = (f4 & 31) << 2;
      f32x4_t x = rg[j];
      u32x2_t hh;
      hh[0] = cvt2bf(x[0], x[1]);
      hh[1] = cvt2bf(x[2], x[3]);
      int idx = r * DD + (cw ^ ((r & 15) << 3));
      *(u32x2_t*)(&CHI[idx]) = hh;
    }
    __syncthreads();                          // vmcnt naturally empty here: no drain cost
    if (ch + 1 < NCHUNK) issue(ch + 1);       // prefetch flies across the raw barrier below

    // ---- compute: wave owns rows [wave*32, wave*32+32) as 2 row-tiles ----
    bf16x8_t ahi[2][4];
#pragma unroll
    for (int rt = 0; rt < 2; ++rt) {
      int r = wave * 32 + rt * 16 + lr;
      int sw = (r & 15) << 3;
#pragma unroll
      for (int ks = 0; ks < 4; ++ks) {
        int c = ks * 32 + lg * 8;
        ahi[rt][ks] = *(const bf16x8_t*)(&CHI[r * DD + (c ^ sw)]);
      }
    }
    float part[2][4] = {{0.f, 0.f, 0.f, 0.f}, {0.f, 0.f, 0.f, 0.f}};
#pragma unroll
    for (int et = 0; et < 8; ++et) {
      bf16x8_t bh[4], bl[4];
#pragma unroll
      for (int ks = 0; ks < 4; ++ks) {
        const int pidx = ((((et << 2) | ks) << 6) | lane) << 3;
        bh[ks] = *(const bf16x8_t*)(&WPKH[pidx]);
        bl[ks] = *(const bf16x8_t*)(&WPKL[pidx]);
      }
      const float wf = wfreg[et];
#pragma unroll
      for (int rt = 0; rt < 2; ++rt) {
        f32x4_t v1 = {0.f, 0.f, 0.f, 0.f};
        f32x4_t v2 = v1;
#pragma unroll
        for (int ks = 0; ks < 4; ++ks) {
          v1 = __builtin_amdgcn_mfma_f32_16x16x32_bf16(ahi[rt][ks], bh[ks], v1, 0, 0, 0);
          v2 = __builtin_amdgcn_mfma_f32_16x16x32_bf16(ahi[rt][ks], bl[ks], v2, 0, 0, 0);
        }
#pragma unroll
        for (int i = 0; i < 4; ++i)
          part[rt][i] += wf * fmaxf(v1[i] + v2[i], 0.f);
      }
    }
    // reduce over e: butterfly across the 16 lanes (lr) sharing rows
#pragma unroll
    for (int rt = 0; rt < 2; ++rt) {
#pragma unroll
      for (int m = 1; m < 16; m <<= 1) {
        part[rt][0] += __shfl_xor(part[rt][0], m, 64);
        part[rt][1] += __shfl_xor(part[rt][1], m, 64);
        part[rt][2] += __shfl_xor(part[rt][2], m, 64);
        part[rt][3] += __shfl_xor(part[rt][3], m, 64);
      }
    }
    if (lr == 0) {                            // C row = 4*lg + i
      long so = (long)b * SS + (long)slice * (NCHUNK * CHROWS) + ch * CHROWS + wave * 32 + lg * 4;
      logits[so + 0]  = part[0][0];
      logits[so + 1]  = part[0][1];
      logits[so + 2]  = part[0][2];
      logits[so + 3]  = part[0][3];
      logits[so + 16] = part[1][0];
      logits[so + 17] = part[1][1];
      logits[so + 18] = part[1][2];
      logits[so + 19] = part[1][3];
    }
    // raw barrier: protect CHI overwrite WITHOUT draining the in-flight prefetch loads
    asm volatile("" ::: "memory");
    __builtin_amdgcn_s_barrier();
    __builtin_amdgcn_sched_barrier(0);
  }
}

// ---- K3: masked softmax over S per batch, in place over logits ----
__global__ void k_softmax(const float* __restrict__ logits, const void* __restrict__ mask,
                          const unsigned int* __restrict__ flag, float* __restrict__ attn) {
  const int b = blockIdx.x;
  const int tid = threadIdx.x;                  // 256
  __shared__ float buf[SS];                     // 32 KiB
  __shared__ float red[4];
  const unsigned mode = *flag;
  const long off = (long)b * SS;
  float mx = -3.4e38f;
  for (int i = tid; i < SS; i += 256) {
    float v = logits[off + i];
    bool m;
    if (mode == 0)      m = ((const int*)mask)[off + i] != 0;
    else if (mode == 1) m = ((const unsigned char*)mask)[off + i] != 0;
    else                m = ((const float*)mask)[off + i] != 0.f;
    if (m) v = -1e12f;
    buf[i] = v;
    mx = fmaxf(mx, v);
  }
#pragma unroll
  for (int m2 = 32; m2; m2 >>= 1) mx = fmaxf(mx, __shfl_xor(mx, m2, 64));
  if ((tid & 63) == 0) red[tid >> 6] = mx;
  __syncthreads();
  mx = fmaxf(fmaxf(red[0], red[1]), fmaxf(red[2], red[3]));
  float sum = 0.f;
  for (int i = tid; i < SS; i += 256) {
    float e = expf(buf[i] - mx);
    buf[i] = e;
    sum += e;
  }
#pragma unroll
  for (int m2 = 32; m2; m2 >>= 1) sum += __shfl_xor(sum, m2, 64);
  __syncthreads();
  if ((tid & 63) == 0) red[tid >> 6] = sum;
  __syncthreads();
  float inv = 1.f / (red[0] + red[1] + red[2] + red[3]);
  for (int i = tid; i < SS; i += 256) attn[off + i] = buf[i] * inv;
}

// ---- K4: partial weighted sums. grid (B, WCH), 256 thr. wpart[b][c][d] ----
__global__ void k_wpartial(const float* __restrict__ attn, const float* __restrict__ ctx,
                           float* __restrict__ wpart) {
  const int b = blockIdx.x, c = blockIdx.y;
  const int tid = threadIdx.x;                  // 256
  __shared__ unsigned short slist[WLEN];
  __shared__ float plist[WLEN];
  __shared__ float part[256];
  __shared__ unsigned cnt;
  if (tid == 0) cnt = 0;
  __syncthreads();
  const long off = (long)b * SS + (long)c * WLEN;
  for (int i = tid; i < WLEN; i += 256) {
    float p = attn[off + i];
    if (p > 1e-8f) {                            // skipped mass <= 8192*1e-8*|ctx| ~ 5e-4
      unsigned k = atomicAdd(&cnt, 1u);
      slist[k] = (unsigned short)i;
      plist[k] = p;
    }
  }
  __syncthreads();
  const int n = (int)cnt;
  const int d = tid & 127;
  const int g = tid >> 7;                       // 2 row-groups
  float a0 = 0.f, a1 = 0.f, a2 = 0.f, a3 = 0.f;
  int k = g;
  for (; k + 6 < n; k += 8) {
    a0 += plist[k]     * ctx[(off + slist[k])     * DD + d];
    a1 += plist[k + 2] * ctx[(off + slist[k + 2]) * DD + d];
    a2 += plist[k + 4] * ctx[(off + slist[k + 4]) * DD + d];
    a3 += plist[k + 6] * ctx[(off + slist[k + 6]) * DD + d];
  }
  for (; k < n; k += 2)
    a0 += plist[k] * ctx[(off + slist[k]) * DD + d];
  part[tid] = (a0 + a1) + (a2 + a3);
  __syncthreads();
  if (tid < 128)
    wpart[((long)b * WCH + c) * DD + tid] = part[tid] + part[tid + 128];
}

// ---- K5: reduce partials, h = tanh([weighted,x]@Wout^T) ----
__global__ void k_out(const float* __restrict__ wpart, const float* __restrict__ inp,
                      const float* __restrict__ Wout, float* __restrict__ hout) {
  const int b = blockIdx.x;
  const int tid = threadIdx.x;                  // 128
  __shared__ float wsh[DD], xin[DD];
  float acc = 0.f;
#pragma unroll
  for (int cc = 0; cc < WCH; ++cc)
    acc += wpart[((long)b * WCH + cc) * DD + tid];
  wsh[tid] = acc;
  xin[tid] = inp[b * DD + tid];
  __syncthreads();
  const float* wr = Wout + tid * (2 * DD);
  float s = 0.f;
#pragma unroll 8
  for (int f = 0; f < DD; ++f) s += wsh[f] * wr[f];
#pragma unroll 8
  for (int f = 0; f < DD; ++f) s += xin[f] * wr[DD + f];
  hout[b * DD + tid] = tanhf(s);
}

extern "C" void kernel_launch(void* const* d_in, const int* in_sizes, int n_in,
                              void* d_out, int out_size, void* d_ws, size_t ws_size,
                              hipStream_t stream) {
  const float* inp  = (const float*)d_in[0];
  const float* ctx  = (const float*)d_in[1];
  const void*  mask = d_in[2];
  const float* Wg   = (const float*)d_in[3];
  const float* Vg   = (const float*)d_in[4];
  const float* Wout = (const float*)d_in[5];

  float* out = (float*)d_out;
  float* h_out = out;                 // [B, D]
  float* attn_out = out + BB * DD;    // [B, S]  (K2 writes raw logits here, K3 normalizes in place)

  char* ws = (char*)d_ws;
  unsigned int*   flag  = (unsigned int*)ws;
  unsigned short* Whi   = (unsigned short*)(ws + 1024);
  unsigned short* Wlo   = (unsigned short*)(ws + 1024 + 32768);
  float*          wv    = (float*)(ws + 1024 + 65536);
  float*          wpart = (float*)(ws + 1024 + 65536 + 65536);   // [B][WCH][DD] = 1 MB

  (void)hipMemsetAsync(flag, 0, 4, stream);
  k_detect  <<<dim3(1024),    dim3(256), 0, stream>>>((const unsigned int*)mask, flag);
  k_splitW  <<<dim3(64),      dim3(256), 0, stream>>>(Wg, Whi, Wlo);
  k_w       <<<dim3(BB),      dim3(DD),  0, stream>>>(inp, Wg, Vg, wv);
  k_logits  <<<dim3(2, BB),   dim3(512), 0, stream>>>(ctx, Whi, Wlo, wv, attn_out);
  k_softmax <<<dim3(BB),      dim3(256), 0, stream>>>(attn_out, mask, flag, attn_out);
  k_wpartial<<<dim3(BB, WCH), dim3(256), 0, stream>>>(attn_out, ctx, wpart);
  k_out     <<<dim3(BB),      dim3(128), 0, stream>>>(wpart, inp, Wout, h_out);
}